// Round 7
// baseline (6412.617 us; speedup 1.0000x reference)
//
#include <hip/hip_runtime.h>

// EdgeAttrHeteroConv — round 7: OUTPUT IS FP32 (reference returns jnp.float32;
// harness doc: "float32 -> float*"). Rounds 0-6 wrote bf16 u16s = only half the
// fp32 buffer, scrambled. The "(bf16,...)" label in the test is hardcoded
// template text; the u<<16 decode in the traceback was source context only.
// Pipeline identical to R6 (protocol + internal sanity all verified there):
//   hs_t = x_src @ Wsrc[t] + bsrc[t]
//   ad_t[j][h] = ((x_dst[j] @ Wdst[t] + bdst[t]) per head) · attn[t][h]
//   logit = leakyrelu(ms·attn[h] + ad[dst][h], 0.2); e = exp(logit)
//   s[dst][h] += e; num[dst][c] += e*ms[c]  (fp32 atomics, single pass;
//   max-shift is a softmax no-op, logits O(5))
//   out = (num/s summed over incoming types) @ Wout[i] + bout[i]  -> fp32
// Tight sentinel diagnostics remain (write 4096*(16+bits) to out[0] on insanity).

typedef unsigned short u16;

__device__ __forceinline__ u16 f2b(float f) {
    if (!(f == f)) f = 0.f;
    union { float f; unsigned int i; } v; v.f = f;
    unsigned int r = v.i + 0x7FFFu + ((v.i >> 16) & 1u);
    return (u16)(r >> 16);
}
__device__ __forceinline__ float b2f(u16 u) {
    union { unsigned int i; float f; } v; v.i = ((unsigned int)u) << 16; return v.f;
}
__device__ __forceinline__ float sigm(float x) { return 1.f / (1.f + expf(-x)); }

// ---------------------------------------------------------------------------
__global__ void zero_k(float* __restrict__ p, int n) {
    int i = blockIdx.x * 256 + threadIdx.x;
    if (i < n) p[i] = 0.f;
}

__global__ void senthost_k(float* out, float v) { out[0] = v; }

// int64 detector (insurance; R6 established int32)
__global__ void detect64_k(const int* __restrict__ a, int n32, int* __restrict__ iflag) {
    __shared__ int oddz;
    if (threadIdx.x == 0) oddz = 0;
    __syncthreads();
    int pairs = min(n32, 8192) / 2;
    int local = 0;
    for (int i = threadIdx.x; i < pairs; i += 256)
        if (a[2 * i + 1] == 0) local++;
    atomicAdd(&oddz, local);
    __syncthreads();
    if (threadIdx.x == 0) iflag[0] = (oddz >= (pairs * 98) / 100) ? 1 : 0;
}

__global__ void precheck_k(const float* __restrict__ s1, const float* __restrict__ n1,
                           int* __restrict__ prefail) {
    int bad = 0;
    for (int i = threadIdx.x; i < 200000; i += 256) if (s1[i] != 0.f) { bad = 1; break; }
    for (int i = threadIdx.x; i < 6400000 && !bad; i += 4096) if (n1[i] != 0.f) { bad = 1; break; }
    if (bad) atomicOr(prefail, 16);
}

// stage-A censuses: maxes, NaNs, empty-segment count (first 10000 s-entries)
__global__ void check_k(const float* __restrict__ hs1, const float* __restrict__ ad1,
                        const float* __restrict__ s1, const float* __restrict__ n1,
                        unsigned* __restrict__ maxb, int* __restrict__ nancnt,
                        int* __restrict__ emptycnt) {
    float smax = 0.f, nmax = 0.f, hmax = 0.f, admax = 0.f;
    int nans = 0, empt = 0;
    for (int i = threadIdx.x; i < 200000; i += 256) {
        float v = s1[i]; if (v != v) nans++; else smax = fmaxf(smax, v);
        float w = ad1[i]; if (w != w) nans++; else admax = fmaxf(admax, fabsf(w));
        if (i < 10000 && v == 0.f) empt++;
    }
    for (int i = threadIdx.x; i < 6400000; i += 2048) {
        float v = n1[i]; if (v != v) nans++; else nmax = fmaxf(nmax, fabsf(v));
    }
    for (int i = threadIdx.x; i < 3840000; i += 2048) {
        float v = hs1[i]; if (v != v) nans++; else hmax = fmaxf(hmax, fabsf(v));
    }
    atomicMax(&maxb[0], __float_as_uint(smax));
    atomicMax(&maxb[1], __float_as_uint(nmax));
    atomicMax(&maxb[2], __float_as_uint(hmax));
    atomicMax(&maxb[3], __float_as_uint(admax));
    if (nans) atomicAdd(nancnt, nans);
    if (empt) atomicAdd(emptycnt, empt);
}

__global__ void sent_k(const int* __restrict__ flags, float* __restrict__ out) {
    const unsigned* u = (const unsigned*)flags;
    float smax = __uint_as_float(u[2]);
    float nmax = __uint_as_float(u[3]);
    float hmax = __uint_as_float(u[4]);
    float admax = __uint_as_float(u[5]);
    int bits = 0;
    if (!(smax > 0.1f && smax < 1e6f)) bits |= 1;
    if (!(nmax > 0.01f && nmax < 1e7f)) bits |= 2;
    if (!(hmax > 0.3f && hmax < 100.f)) bits |= 4;
    if (!(admax > 0.005f && admax < 100.f)) bits |= 8;
    bits |= flags[1];                         // bit4: zero-fill integrity
    if (flags[6] > 0) bits |= 32;             // NaNs
    if (flags[7] > 500) bits |= 64;           // >5% empty segments: bad scatter
    if (bits) out[0] = 4096.f * (float)(16 + bits);
}

// ---------------------------------------------------------------------------
__global__ void gtbl_k(const float* __restrict__ temb, const float* __restrict__ semb,
                       const float* __restrict__ Wg, const float* __restrict__ bg,
                       float* __restrict__ gtbl) {
    int idx = blockIdx.x * 256 + threadIdx.x;
    if (idx >= 8192) return;
    int combo = idx >> 7, c = idx & 127;
    int a = combo >> 3, b = combo & 7;
    float s = bg[c];
    for (int k = 0; k < 32; k++) s += temb[a * 32 + k] * Wg[k * 128 + c];
    for (int k = 0; k < 32; k++) s += semb[b * 32 + k] * Wg[(32 + k) * 128 + c];
    gtbl[combo * 128 + c] = sigm(s);
}

__global__ void hsrow_k(const float* __restrict__ x, const float* __restrict__ W,
                        const float* __restrict__ bias, float* __restrict__ hs, int N) {
    int tid = threadIdx.x;
    int row = blockIdx.x * 2 + (tid >> 7);
    int c = tid & 127;
    if (row >= N) return;
    float acc = bias[c];
    for (int k = 0; k < 128; k++)
        acc += x[(size_t)row * 128 + k] * W[k * 128 + c];
    hs[(size_t)row * 128 + c] = acc;
}

__global__ void adirect_k(const float* __restrict__ x, const float* __restrict__ Wdst_t,
                          const float* __restrict__ bdst_t, const float* __restrict__ attn_t,
                          float* __restrict__ ad, int N) {
    int lane = threadIdx.x & 63;
    int gw = (blockIdx.x * 256 + threadIdx.x) >> 6;
    int nw = gridDim.x * 4;
    int c0 = 2 * lane, c1 = 2 * lane + 1;
    float aa = attn_t[c0], ab = attn_t[c1];
    for (int j = gw; j < N; j += nw) {
        float ha = bdst_t[c0], hb = bdst_t[c1];
        for (int k = 0; k < 128; k++) {
            float xk = x[(size_t)j * 128 + k];
            ha += xk * Wdst_t[k * 128 + c0];
            hb += xk * Wdst_t[k * 128 + c1];
        }
        float part = ha * aa + hb * ab;
        part += __shfl_xor(part, 1);
        part += __shfl_xor(part, 2);
        part += __shfl_xor(part, 4);
        part += __shfl_xor(part, 8);
        if ((lane & 15) == 0) ad[j * 4 + (lane >> 4)] = part;
    }
}

// MODE 0: plain. MODE 1: categorical gate table (t0). MODE 2: fused cont. gate (t2).
template <int MODE>
__global__ __launch_bounds__(256) void edge_k(const float* __restrict__ hs,
                                              const float* __restrict__ ad,
                                              const int* __restrict__ src,
                                              const int* __restrict__ dst,
                                              const float* __restrict__ attn_t,
                                              const int* __restrict__ cg,
                                              const float* __restrict__ gtbl,
                                              const float* __restrict__ cp,
                                              const float* __restrict__ W1c,
                                              const float* __restrict__ b1c,
                                              const float* __restrict__ W2c,
                                              const float* __restrict__ b2c,
                                              float* __restrict__ sbuf,
                                              float* __restrict__ num,
                                              const int* __restrict__ iflagp,
                                              int E, int Ns, int Nd) {
    __shared__ u16 w2l[MODE == 2 ? 16384 : 1];
    if (MODE == 2) {
        for (int i = threadIdx.x; i < 16384; i += 256) w2l[i] = f2b(W2c[i]);
        __syncthreads();
    }
    const bool i64 = iflagp[0] != 0;
    int lane = threadIdx.x & 63;
    int gw = (blockIdx.x * 256 + threadIdx.x) >> 6;
    int nw = gridDim.x * 4;
    int c0 = 2 * lane, c1 = 2 * lane + 1;
    float ax = attn_t[c0], ay = attn_t[c1];
    float w1a = 0.f, w1b = 0.f, w1c_ = 0.f, w1d = 0.f, w1e = 0.f, w1f = 0.f;
    float b1a = 0.f, b1b = 0.f, bc2a = 0.f, bc2b = 0.f;
    if (MODE == 2) {
        w1a = W1c[0 * 128 + c0]; w1b = W1c[1 * 128 + c0]; w1c_ = W1c[2 * 128 + c0];
        w1d = W1c[0 * 128 + c1]; w1e = W1c[1 * 128 + c1]; w1f = W1c[2 * 128 + c1];
        b1a = b1c[c0]; b1b = b1c[c1];
        bc2a = b2c[c0]; bc2b = b2c[c1];
    }
    int h = lane >> 4;
    for (int e = gw; e < E; e += nw) {
        int si, di;
        if (i64) {
            si = (int)((const long long*)src)[e];
            di = (int)((const long long*)dst)[e];
        } else {
            si = src[e]; di = dst[e];
        }
        si = si < 0 ? 0 : (si >= Ns ? Ns - 1 : si);
        di = di < 0 ? 0 : (di >= Nd ? Nd - 1 : di);
        float mx = hs[(size_t)si * 128 + c0];
        float my = hs[(size_t)si * 128 + c1];
        if (MODE == 1) {
            int a, b;
            if (i64) {
                a = (int)((const long long*)cg)[2 * e] & 7;
                b = (int)((const long long*)cg)[2 * e + 1] & 7;
            } else {
                a = cg[2 * e] & 7; b = cg[2 * e + 1] & 7;
            }
            mx *= gtbl[(a * 8 + b) * 128 + c0];
            my *= gtbl[(a * 8 + b) * 128 + c1];
        } else if (MODE == 2) {
            float p0 = cp[(size_t)e * 3 + 0];
            float p1 = cp[(size_t)e * 3 + 1];
            float p2 = cp[(size_t)e * 3 + 2];
            float z0 = b1a + p0 * w1a + p1 * w1b + p2 * w1c_;
            float z1 = b1b + p0 * w1d + p1 * w1e + p2 * w1f;
            float u0 = 0.5f * z0 * (1.f + erff(z0 * 0.70710678118654752f));
            float u1 = 0.5f * z1 * (1.f + erff(z1 * 0.70710678118654752f));
            float acc0 = bc2a, acc1 = bc2b;
            for (int kk = 0; kk < 64; kk++) {
                float ua = __shfl(u0, kk);
                float ub = __shfl(u1, kk);
                acc0 += ua * b2f(w2l[(2 * kk) * 128 + c0]) + ub * b2f(w2l[(2 * kk + 1) * 128 + c0]);
                acc1 += ua * b2f(w2l[(2 * kk) * 128 + c1]) + ub * b2f(w2l[(2 * kk + 1) * 128 + c1]);
            }
            mx *= sigm(acc0);
            my *= sigm(acc1);
        }
        float p = mx * ax + my * ay;
        p += __shfl_xor(p, 1);
        p += __shfl_xor(p, 2);
        p += __shfl_xor(p, 4);
        p += __shfl_xor(p, 8);
        float logit = p + ad[di * 4 + h];
        logit = logit > 0.f ? logit : 0.2f * logit;
        logit = fminf(fmaxf(logit, -60.f), 60.f);
        float ex = expf(logit);
        if ((lane & 15) == 0) atomicAdd(&sbuf[di * 4 + h], ex);
        atomicAdd(&num[(size_t)di * 128 + c0], ex * mx);
        atomicAdd(&num[(size_t)di * 128 + c1], ex * my);
    }
}

// out[row][c] = bo[c] + sum_k agg(row,k)*Wo[k][c] ; FP32 output
__global__ void outrow_k(const float* __restrict__ numA, const float* __restrict__ sA,
                         const float* __restrict__ numB, const float* __restrict__ sB,
                         const float* __restrict__ Wo, const float* __restrict__ bo,
                         float* __restrict__ out, int N) {
    int tid = threadIdx.x;
    int row = blockIdx.x * 2 + (tid >> 7);
    int c = tid & 127;
    if (row >= N) return;
    float acc = bo[c];
    for (int k = 0; k < 128; k++) {
        float a = 0.f;
        if (numA) {
            float sa = sA[row * 4 + (k >> 5)];
            if (sa > 0.f) a += numA[(size_t)row * 128 + k] / sa;
        }
        if (numB) {
            float sb = sB[row * 4 + (k >> 5)];
            if (sb > 0.f) a += numB[(size_t)row * 128 + k] / sb;
        }
        acc += a * Wo[k * 128 + c];
    }
    out[(size_t)row * 128 + c] = acc;
}

// ---------------------------------------------------------------------------
extern "C" void kernel_launch(void* const* d_in, const int* in_sizes, int n_in,
                              void* d_out, int out_size, void* d_ws, size_t ws_size,
                              hipStream_t stream) {
    static const int expect[29] = {
        6400000, 3840000, 1280000, 640000,
        500000, 500000, 500000, 500000, 250000, 250000, 250000, 250000,
        1000000, 750000, 65536, 512, 65536, 512, 512, 320, 256,
        8192, 128, 384, 128, 16384, 128, 65536, 512};
    int bad = 0;
    if (n_in != 29) bad = 1;
    else {
        for (int i = 0; i < 29; i++)
            if (in_sizes[i] != expect[i]) { bad = 4 + i; break; }
    }
    if (!bad && out_size != 12160000) bad = 2;
    if (!bad && ws_size < (size_t)63425536) bad = 3;
    if (bad) {
        senthost_k<<<1, 1, 0, stream>>>((float*)d_out, 4096.f * (float)bad);
        return;
    }

    const float* x_chem = (const float*)d_in[0];
    const float* x_gene = (const float*)d_in[1];
    const float* x_dis  = (const float*)d_in[2];
    const float* x_path = (const float*)d_in[3];
    const int* src0 = (const int*)d_in[4];  const int* dst0 = (const int*)d_in[5];
    const int* src1 = (const int*)d_in[6];  const int* dst1 = (const int*)d_in[7];
    const int* src2 = (const int*)d_in[8];  const int* dst2 = (const int*)d_in[9];
    const int* src3 = (const int*)d_in[10]; const int* dst3 = (const int*)d_in[11];
    const int*   cg   = (const int*)d_in[12];
    const float* cp   = (const float*)d_in[13];
    const float* Wsrc = (const float*)d_in[14]; const float* bsrc = (const float*)d_in[15];
    const float* Wdst = (const float*)d_in[16]; const float* bdst = (const float*)d_in[17];
    const float* attn = (const float*)d_in[18];
    const float* temb = (const float*)d_in[19]; const float* semb = (const float*)d_in[20];
    const float* Wg   = (const float*)d_in[21]; const float* bg   = (const float*)d_in[22];
    const float* W1c  = (const float*)d_in[23]; const float* b1c  = (const float*)d_in[24];
    const float* W2c  = (const float*)d_in[25]; const float* b2c  = (const float*)d_in[26];
    const float* Wout = (const float*)d_in[27]; const float* bout = (const float*)d_in[28];

    constexpr int NC = 50000, NG = 30000, ND = 10000, NP = 5000;
    constexpr int E0 = 500000, E1 = 500000, E2 = 250000, E3 = 250000;

    char* ws = (char*)d_ws;
    float* gt    = (float*)ws;            // [64][128] f32 = 32768 B
    int*   flags = (int*)(ws + 32768);    // [0]=i64 [1]=prefail [2..5]=max [6]=nan [7]=empty
    char*  A     = ws + 65536;            // stage arena (<= 63,360,000 B)

    float* out = (float*)d_out;
    float* out_chem = out;
    float* out_gene = out + (size_t)NC * 128;
    float* out_dis  = out + (size_t)(NC + NG) * 128;
    float* out_path = out + (size_t)(NC + NG + ND) * 128;

    zero_k<<<1, 256, 0, stream>>>((float*)flags, 8);
    detect64_k<<<1, 256, 0, stream>>>(src0, E0, flags);
    gtbl_k<<<32, 256, 0, stream>>>(temb, semb, Wg, bg, gt);

    // ---------- STAGE A: chemical output (t1: gene -> chemical) ----------
    {
        float* hs1 = (float*)(A);
        float* ad1 = (float*)(A + 15360000);
        float* s1  = (float*)(A + 16160000);
        float* n1  = (float*)(A + 16960000);
        zero_k<<<782, 256, 0, stream>>>(s1, 200000);
        zero_k<<<25000, 256, 0, stream>>>(n1, 6400000);
        precheck_k<<<1, 256, 0, stream>>>(s1, n1, flags + 1);
        hsrow_k<<<(NG + 1) / 2, 256, 0, stream>>>(x_gene, Wsrc + 1 * 16384, bsrc + 1 * 128, hs1, NG);
        adirect_k<<<1024, 256, 0, stream>>>(x_chem, Wdst + 1 * 16384, bdst + 1 * 128, attn + 1 * 128, ad1, NC);
        edge_k<0><<<2048, 256, 0, stream>>>(hs1, ad1, src1, dst1, attn + 1 * 128,
                                            nullptr, nullptr, nullptr, nullptr, nullptr, nullptr, nullptr,
                                            s1, n1, flags, E1, NG, NC);
        check_k<<<1, 256, 0, stream>>>(hs1, ad1, s1, n1, (unsigned*)(flags + 2), flags + 6, flags + 7);
        outrow_k<<<(NC + 1) / 2, 256, 0, stream>>>(n1, s1, nullptr, nullptr,
                                                   Wout + 0 * 16384, bout + 0 * 128, out_chem, NC);
    }

    // ---------- STAGE B: pathway output (t2: chemical -> pathway) ----------
    {
        float* hs2 = (float*)(A);
        float* ad2 = (float*)(A + 25600000);
        float* s2  = (float*)(A + 25680000);
        float* n2  = (float*)(A + 25760000);
        zero_k<<<79, 256, 0, stream>>>(s2, 20000);
        zero_k<<<2500, 256, 0, stream>>>(n2, 640000);
        hsrow_k<<<(NC + 1) / 2, 256, 0, stream>>>(x_chem, Wsrc + 2 * 16384, bsrc + 2 * 128, hs2, NC);
        adirect_k<<<512, 256, 0, stream>>>(x_path, Wdst + 2 * 16384, bdst + 2 * 128, attn + 2 * 128, ad2, NP);
        edge_k<2><<<2048, 256, 0, stream>>>(hs2, ad2, src2, dst2, attn + 2 * 128,
                                            nullptr, nullptr, cp, W1c, b1c, W2c, b2c,
                                            s2, n2, flags, E2, NC, NP);
        outrow_k<<<(NP + 1) / 2, 256, 0, stream>>>(n2, s2, nullptr, nullptr,
                                                   Wout + 3 * 16384, bout + 3 * 128, out_path, NP);
    }

    // ---------- STAGE C: gene output (t0 + t3) ----------
    {
        float* hs0 = (float*)(A);
        float* hs3 = (float*)(A + 25600000);
        float* ad0 = (float*)(A + 30720000);
        float* ad3 = (float*)(A + 31200000);
        float* s0  = (float*)(A + 31680000);
        float* s3  = (float*)(A + 32160000);
        float* n0  = (float*)(A + 32640000);
        float* n3  = (float*)(A + 48000000);
        zero_k<<<469, 256, 0, stream>>>(s0, 120000);
        zero_k<<<469, 256, 0, stream>>>(s3, 120000);
        zero_k<<<15000, 256, 0, stream>>>(n0, 3840000);
        zero_k<<<15000, 256, 0, stream>>>(n3, 3840000);
        hsrow_k<<<(NC + 1) / 2, 256, 0, stream>>>(x_chem, Wsrc + 0 * 16384, bsrc + 0 * 128, hs0, NC);
        hsrow_k<<<(ND + 1) / 2, 256, 0, stream>>>(x_dis,  Wsrc + 3 * 16384, bsrc + 3 * 128, hs3, ND);
        adirect_k<<<1024, 256, 0, stream>>>(x_gene, Wdst + 0 * 16384, bdst + 0 * 128, attn + 0 * 128, ad0, NG);
        adirect_k<<<1024, 256, 0, stream>>>(x_gene, Wdst + 3 * 16384, bdst + 3 * 128, attn + 3 * 128, ad3, NG);
        edge_k<1><<<2048, 256, 0, stream>>>(hs0, ad0, src0, dst0, attn + 0 * 128,
                                            cg, gt, nullptr, nullptr, nullptr, nullptr, nullptr,
                                            s0, n0, flags, E0, NC, NG);
        edge_k<0><<<2048, 256, 0, stream>>>(hs3, ad3, src3, dst3, attn + 3 * 128,
                                            nullptr, nullptr, nullptr, nullptr, nullptr, nullptr, nullptr,
                                            s3, n3, flags, E3, ND, NG);
        outrow_k<<<(NG + 1) / 2, 256, 0, stream>>>(n0, s0, n3, s3,
                                                   Wout + 1 * 16384, bout + 1 * 128, out_gene, NG);
    }

    // ---------- STAGE D: disease output (no incoming edges: bias only) ------
    outrow_k<<<(ND + 1) / 2, 256, 0, stream>>>(nullptr, nullptr, nullptr, nullptr,
                                               Wout + 2 * 16384, bout + 2 * 128, out_dis, ND);

    // ---------- diagnosis verdict (overwrites out[0] only on failure) -------
    sent_k<<<1, 1, 0, stream>>>(flags, out);
}